// Round 1
// baseline (1222.343 us; speedup 1.0000x reference)
//
#include <hip/hip_runtime.h>

// SparseLinear: out[b,k] = dot(embed[b,:], sp_weight[shortlist[b,k],:]) + sp_bias[shortlist[b,k]]
// B=512, K=800, D=512, L=500000. fp32 throughout.
//
// Layout: one wave per output element. Lane i holds 8 embed floats (2x float4)
// in registers (reused across all k of the block's batch row). Per k:
// two coalesced float4 loads cover the 2KB weight row, 8 FMAs, 6-step shuffle
// reduce. 2-k unroll for memory-level parallelism.

#define DDIM 512
#define KTOT 800
#define KCHUNKS 4
#define KPB (KTOT / KCHUNKS)   // 200 k per block

__global__ __launch_bounds__(256, 4)
void sparse_linear_kernel(const float* __restrict__ embed,
                          const int* __restrict__ shortlist,
                          const float* __restrict__ sp_weight,
                          const float* __restrict__ sp_bias,
                          float* __restrict__ out) {
    const int b     = blockIdx.x;
    const int kbase = blockIdx.y * KPB;
    const int wave  = threadIdx.x >> 6;
    const int lane  = threadIdx.x & 63;

    // Each lane's 8 embed floats: floats [4*lane, 4*lane+4) and [256+4*lane, ...)
    const float4* e4 = (const float4*)(embed + (size_t)b * DDIM);
    const float4 e0 = e4[lane];
    const float4 e1 = e4[64 + lane];

    const int* sl_row = shortlist + (size_t)b * KTOT;
    float* out_row = out + (size_t)b * KTOT;

    // 4 waves, each handles pairs of k: wave w covers k = kbase + 2w, 2w+1, 2w+8, ...
    for (int k = kbase + wave * 2; k < kbase + KPB; k += 8) {
        const int ia = sl_row[k];
        const int ib = sl_row[k + 1];
        const float4* wa = (const float4*)(sp_weight + (size_t)ia * DDIM);
        const float4* wb = (const float4*)(sp_weight + (size_t)ib * DDIM);
        const float4 a0 = wa[lane];
        const float4 a1 = wa[64 + lane];
        const float4 b0 = wb[lane];
        const float4 b1 = wb[64 + lane];

        float pa = a0.x * e0.x + a0.y * e0.y + a0.z * e0.z + a0.w * e0.w
                 + a1.x * e1.x + a1.y * e1.y + a1.z * e1.z + a1.w * e1.w;
        float pb = b0.x * e0.x + b0.y * e0.y + b0.z * e0.z + b0.w * e0.w
                 + b1.x * e1.x + b1.y * e1.y + b1.z * e1.z + b1.w * e1.w;

        // interleaved 64-lane reductions
        #pragma unroll
        for (int off = 32; off > 0; off >>= 1) {
            pa += __shfl_down(pa, off, 64);
            pb += __shfl_down(pb, off, 64);
        }

        if (lane == 0) {
            out_row[k]     = pa + sp_bias[ia];
            out_row[k + 1] = pb + sp_bias[ib];
        }
    }
}

extern "C" void kernel_launch(void* const* d_in, const int* in_sizes, int n_in,
                              void* d_out, int out_size, void* d_ws, size_t ws_size,
                              hipStream_t stream) {
    const float* embed     = (const float*)d_in[0];
    const int*   shortlist = (const int*)d_in[1];
    const float* sp_weight = (const float*)d_in[2];
    const float* sp_bias   = (const float*)d_in[3];
    float* out = (float*)d_out;

    dim3 grid(512, KCHUNKS);
    dim3 block(256);
    hipLaunchKernelGGL(sparse_linear_kernel, grid, block, 0, stream,
                       embed, shortlist, sp_weight, sp_bias, out);
}